// Round 2
// baseline (105.765 us; speedup 1.0000x reference)
//
#include <hip/hip_runtime.h>
#include <math.h>

#define HS    200   // HIST_SIZE
#define DIMV  64    // DIM
#define HID   32    // HIDDEN
#define NTH   256
#define NW    32    // u32 words (bf16 pairs) per hist row

// round-to-nearest-even f32 -> bf16 (bits in low 16)
__device__ __forceinline__ unsigned bf16_rne(float x) {
    unsigned u = __float_as_uint(x);
    return (u + 0x7FFFu + ((u >> 16) & 1u)) >> 16;
}
// pair-granular XOR swizzle: word w of row r stored at w ^ ((r&15)<<1)
__device__ __forceinline__ int swz(int r, int w) { return w ^ ((r & 15) << 1); }

__global__ __launch_bounds__(NTH, 4) void din_attn_kernel(
    const float* __restrict__ cand,   // B x 64
    const float* __restrict__ hist,   // B x 200 x 64
    const int*   __restrict__ lens,   // B
    const float* __restrict__ W1,     // 256 x 32
    const float* __restrict__ B1,     // 32
    const float* __restrict__ W2,     // 32
    const float* __restrict__ B2,     // 1
    float* __restrict__ out)          // B x 64
{
    __shared__ unsigned s_h[HS * NW];   // 25600 B  (bf16-pair hist, swizzled)
    __shared__ float s_M[DIMV * HID];   // 8192 B   (fused per-batch matrix)
    __shared__ float s_sc[HS];          // 800 B
    __shared__ float s_c[HID];          // 128 B
    __shared__ float s_w2[HID];         // 128 B
    __shared__ float s_red[8];          // 32 B
    __shared__ float s_part[NTH];       // 1024 B   -> ~35.9 KB total

    const int b   = blockIdx.x;
    const int tid = threadIdx.x;

    // ---------------- P0: stage hist (bf16 pairs), build M and c ----------------
    const float4* hp = (const float4*)(hist + (size_t)b * (HS * DIMV));
    #pragma unroll
    for (int j = 0; j < 13; ++j) {
        int i = tid + j * NTH;                 // float4 index, 3200 total
        if (i < HS * DIMV / 4) {
            float4 v = hp[i];
            int r  = i >> 4;                   // hist row (16 float4 per row)
            int w0 = (i & 15) << 1;            // first u32 word (even)
            unsigned lo = bf16_rne(v.x) | (bf16_rne(v.y) << 16);
            unsigned hi = bf16_rne(v.z) | (bf16_rne(v.w) << 16);
            *(uint2*)&s_h[r * NW + swz(r, w0)] = make_uint2(lo, hi);
        }
    }
    {   // M[f][h] = Wb - Wd + cand[f]*Wc   (rows: Wa=0..63, Wb=64.., Wc=128.., Wd=192..)
        const int f0 = tid >> 5, h = tid & 31;
        #pragma unroll
        for (int j = 0; j < 8; ++j) {
            int f = f0 + (j << 3);
            float cf = cand[(size_t)b * DIMV + f];
            s_M[f * HID + h] = W1[(DIMV + f) * HID + h]
                             - W1[(3 * DIMV + f) * HID + h]
                             + cf * W1[(2 * DIMV + f) * HID + h];
        }
    }
    if (tid < HID) {   // c[h] = sum_f cand[f]*(Wa+Wd)[f][h] + B1[h]
        float acc = B1[tid];
        #pragma unroll 8
        for (int f = 0; f < DIMV; ++f)
            acc += cand[(size_t)b * DIMV + f] *
                   (W1[f * HID + tid] + W1[(3 * DIMV + f) * HID + tid]);
        s_c[tid]  = acc;
        s_w2[tid] = W2[tid];
    }
    __syncthreads();

    // ---------------- P1: scores, ONE ROW PER THREAD (no cross-lane ops) --------
    {
        const int r = (tid < HS) ? tid : 0;    // threads 200..255 compute a dummy
        const int rbase = r * NW;
        float acc[HID];
        #pragma unroll
        for (int h = 0; h < HID; ++h) acc[h] = s_c[h];
        #pragma unroll 4
        for (int fb = 0; fb < 16; ++fb) {      // 4 f-values per iteration
            uint2 u = *(const uint2*)&s_h[rbase + swz(r, fb << 1)];
            float hf[4];
            hf[0] = __uint_as_float(u.x << 16);
            hf[1] = __uint_as_float(u.x & 0xFFFF0000u);
            hf[2] = __uint_as_float(u.y << 16);
            hf[3] = __uint_as_float(u.y & 0xFFFF0000u);
            #pragma unroll
            for (int df = 0; df < 4; ++df) {
                const float4* mrow = (const float4*)&s_M[((fb << 2) + df) * HID]; // wave-uniform -> broadcast
                #pragma unroll
                for (int q = 0; q < 8; ++q) {
                    float4 mv = mrow[q];
                    acc[(q << 2) + 0] = fmaf(hf[df], mv.x, acc[(q << 2) + 0]);
                    acc[(q << 2) + 1] = fmaf(hf[df], mv.y, acc[(q << 2) + 1]);
                    acc[(q << 2) + 2] = fmaf(hf[df], mv.z, acc[(q << 2) + 2]);
                    acc[(q << 2) + 3] = fmaf(hf[df], mv.w, acc[(q << 2) + 3]);
                }
            }
        }
        float score = 0.f;
        #pragma unroll
        for (int h = 0; h < HID; ++h) score = fmaf(fmaxf(acc[h], 0.f), s_w2[h], score);
        if (tid < HS) s_sc[tid] = score + B2[0];
    }
    __syncthreads();

    // ---------------- P2: masked scaled softmax (full-wave shuffles only) -------
    const int len = lens[b];
    float sc = -INFINITY;
    if (tid < HS) sc = ((tid < len) ? s_sc[tid] : -4294967296.0f) * 0.125f;
    float mx = sc;
    #pragma unroll
    for (int o = 32; o; o >>= 1) mx = fmaxf(mx, __shfl_xor(mx, o));
    if ((tid & 63) == 0) s_red[tid >> 6] = mx;
    __syncthreads();
    const float gmax = fmaxf(fmaxf(s_red[0], s_red[1]), fmaxf(s_red[2], s_red[3]));
    float e = 0.f;
    if (tid < HS) { e = __expf(sc - gmax); s_sc[tid] = e; }
    float sm = e;
    #pragma unroll
    for (int o = 32; o; o >>= 1) sm += __shfl_xor(sm, o);
    if ((tid & 63) == 0) s_red[4 + (tid >> 6)] = sm;
    __syncthreads();
    const float inv = 1.0f / ((s_red[4] + s_red[5]) + (s_red[6] + s_red[7]));

    // ---------------- P3: weighted sum from LDS bf16 ----------------------------
    {
        const int d = tid & 63, ch = tid >> 6;
        const int w = d >> 1;
        float accd = 0.f;
        for (int s = ch; s < HS; s += 4) {
            unsigned u = s_h[s * NW + swz(s, w)];
            float hv = __uint_as_float((d & 1) ? (u & 0xFFFF0000u) : (u << 16));
            accd = fmaf(s_sc[s], hv, accd);    // s_sc broadcast; banks conflict-free
        }
        s_part[tid] = accd;                    // tid == ch*64 + d
    }
    __syncthreads();
    if (tid < DIMV) {
        float res = (s_part[tid] + s_part[DIMV + tid]) +
                    (s_part[2 * DIMV + tid] + s_part[3 * DIMV + tid]);
        out[(size_t)b * DIMV + tid] = res * inv;
    }
}

extern "C" void kernel_launch(void* const* d_in, const int* in_sizes, int n_in,
                              void* d_out, int out_size, void* d_ws, size_t ws_size,
                              hipStream_t stream) {
    const float* cand = (const float*)d_in[0];
    const float* hist = (const float*)d_in[1];
    const int*   lens = (const int*)d_in[2];
    const float* W1   = (const float*)d_in[3];
    const float* B1   = (const float*)d_in[4];
    const float* W2   = (const float*)d_in[5];
    const float* B2   = (const float*)d_in[6];
    float* out = (float*)d_out;

    const int B = in_sizes[0] / DIMV;  // 4096
    din_attn_kernel<<<B, NTH, 0, stream>>>(cand, hist, lens, W1, B1, W2, B2, out);
}

// Round 3
// 90.752 us; speedup vs baseline: 1.1654x; 1.1654x over previous
//
#include <hip/hip_runtime.h>
#include <math.h>

#define HS    200   // HIST_SIZE
#define DIMV  64    // DIM
#define HID   32    // HIDDEN
#define NTH   256
#define NW    32    // u32 words (bf16 pairs) per hist row

// round-to-nearest-even f32 -> bf16 (bits in low 16)
__device__ __forceinline__ unsigned bf16_rne(float x) {
    unsigned u = __float_as_uint(x);
    return (u + 0x7FFFu + ((u >> 16) & 1u)) >> 16;
}
// pair-granular XOR swizzle: word w of row r stored at w ^ ((r&15)<<1)
__device__ __forceinline__ int swz(int r, int w) { return w ^ ((r & 15) << 1); }

__global__ __launch_bounds__(NTH, 4) void din_attn_kernel(
    const float* __restrict__ cand,   // B x 64
    const float* __restrict__ hist,   // B x 200 x 64
    const int*   __restrict__ lens,   // B
    const float* __restrict__ W1,     // 256 x 32
    const float* __restrict__ B1,     // 32
    const float* __restrict__ W2,     // 32
    const float* __restrict__ B2,     // 1
    float* __restrict__ out)          // B x 64
{
    __shared__ unsigned s_h[HS * NW];   // 25600 B  (bf16-pair hist, swizzled)
    __shared__ float s_M[DIMV * HID];   // 8192 B
    __shared__ float s_sc[HS];          // 800 B
    __shared__ float s_c[HID];          // 128 B
    __shared__ float s_w2[HID];         // 128 B
    __shared__ float s_red[8];          // 32 B
    __shared__ float s_part[NTH];       // 1024 B  -> 35904 B total (4 blocks/CU)

    const int b   = blockIdx.x;
    const int tid = threadIdx.x;

    // ---------------- P0: stage hist (bf16 pairs) + build M, c ------------------
    const float4* hp = (const float4*)(hist + (size_t)b * (HS * DIMV));
    float4 v[13];
    #pragma unroll
    for (int j = 0; j < 12; ++j) v[j] = hp[tid + j * NTH];
    const bool tail = tid < (HS * DIMV / 4 - 12 * NTH);   // 128 threads
    if (tail) v[12] = hp[12 * NTH + tid];

    {   // M[f][h] = Wb - Wd + cand[f]*Wc  (row blocks: Wa|Wb|Wc|Wd)
        const int f0 = tid >> 5, h = tid & 31;
        #pragma unroll
        for (int j = 0; j < 8; ++j) {
            int f = f0 + (j << 3);
            float cf = cand[(size_t)b * DIMV + f];
            s_M[f * HID + h] = W1[(DIMV + f) * HID + h]
                             - W1[(3 * DIMV + f) * HID + h]
                             + cf * W1[(2 * DIMV + f) * HID + h];
        }
    }
    if (tid < HID) {   // c[h] = sum_f cand[f]*(Wa+Wd)[f][h] + B1[h]
        float acc = B1[tid];
        #pragma unroll 8
        for (int f = 0; f < DIMV; ++f)
            acc += cand[(size_t)b * DIMV + f] *
                   (W1[f * HID + tid] + W1[(3 * DIMV + f) * HID + tid]);
        s_c[tid]  = acc;
        s_w2[tid] = W2[tid];
    }

    #pragma unroll
    for (int j = 0; j < 12; ++j) {
        int i = tid + j * NTH;
        int r  = i >> 4;                    // hist row (16 float4 per row)
        int w0 = (i & 15) << 1;             // first u32 word (even)
        unsigned lo = bf16_rne(v[j].x) | (bf16_rne(v[j].y) << 16);
        unsigned hi = bf16_rne(v[j].z) | (bf16_rne(v[j].w) << 16);
        *(uint2*)&s_h[r * NW + swz(r, w0)] = make_uint2(lo, hi);
    }
    if (tail) {
        int i = 12 * NTH + tid;
        int r = i >> 4, w0 = (i & 15) << 1;
        unsigned lo = bf16_rne(v[12].x) | (bf16_rne(v[12].y) << 16);
        unsigned hi = bf16_rne(v[12].z) | (bf16_rne(v[12].w) << 16);
        *(uint2*)&s_h[r * NW + swz(r, w0)] = make_uint2(lo, hi);
    }
    __syncthreads();

    // ---------------- P1: scores, 4 rows x 8 h per thread, register-tiled -------
    // quad q = tid>>2 owns rows {q, q+50, q+100, q+150}; lane tid&3 owns h0=8*(tid&3).
    // ALL 256 lanes execute (quads >= 50 compute a clamped dummy, never write),
    // so the 4-lane shuffle reduction runs with a full exec mask.
    {
        const int sgRaw = tid >> 2;
        const int sg    = (sgRaw < 50) ? sgRaw : 49;
        const int h0    = (tid & 3) << 3;
        const float b2  = B2[0];

        float4 c0 = *(const float4*)&s_c[h0];
        float4 c1 = *(const float4*)&s_c[h0 + 4];
        float acc[4][8];
        #pragma unroll
        for (int si = 0; si < 4; ++si) {
            acc[si][0] = c0.x; acc[si][1] = c0.y; acc[si][2] = c0.z; acc[si][3] = c0.w;
            acc[si][4] = c1.x; acc[si][5] = c1.y; acc[si][6] = c1.z; acc[si][7] = c1.w;
        }

        #pragma unroll 4
        for (int fb = 0; fb < 16; ++fb) {
            uint2 hu[4];
            #pragma unroll
            for (int si = 0; si < 4; ++si) {
                int r = sg + 50 * si;
                hu[si] = *(const uint2*)&s_h[r * NW + swz(r, fb << 1)];
            }
            float mm[4][8];
            #pragma unroll
            for (int df = 0; df < 4; ++df) {
                const float4* mr = (const float4*)&s_M[(((fb << 2) + df) * HID) + h0];
                float4 a = mr[0], bq = mr[1];
                mm[df][0] = a.x;  mm[df][1] = a.y;  mm[df][2] = a.z;  mm[df][3] = a.w;
                mm[df][4] = bq.x; mm[df][5] = bq.y; mm[df][6] = bq.z; mm[df][7] = bq.w;
            }
            #pragma unroll
            for (int si = 0; si < 4; ++si) {
                float hf[4];
                hf[0] = __uint_as_float(hu[si].x << 16);
                hf[1] = __uint_as_float(hu[si].x & 0xFFFF0000u);
                hf[2] = __uint_as_float(hu[si].y << 16);
                hf[3] = __uint_as_float(hu[si].y & 0xFFFF0000u);
                #pragma unroll
                for (int df = 0; df < 4; ++df)
                    #pragma unroll
                    for (int j = 0; j < 8; ++j)
                        acc[si][j] = fmaf(hf[df], mm[df][j], acc[si][j]);
            }
        }

        float4 w0v = *(const float4*)&s_w2[h0];
        float4 w1v = *(const float4*)&s_w2[h0 + 4];
        float w2v[8] = {w0v.x, w0v.y, w0v.z, w0v.w, w1v.x, w1v.y, w1v.z, w1v.w};

        float sp[4];
        #pragma unroll
        for (int si = 0; si < 4; ++si) {
            float t = 0.f;
            #pragma unroll
            for (int j = 0; j < 8; ++j) t = fmaf(fmaxf(acc[si][j], 0.f), w2v[j], t);
            sp[si] = t;
        }
        #pragma unroll
        for (int si = 0; si < 4; ++si) {          // full-wave, exec-uniform
            sp[si] += __shfl_xor(sp[si], 1);
            sp[si] += __shfl_xor(sp[si], 2);
        }
        if ((tid & 3) == 0 && sgRaw < 50) {
            #pragma unroll
            for (int si = 0; si < 4; ++si) s_sc[sg + 50 * si] = sp[si] + b2;
        }
    }
    __syncthreads();

    // ---------------- P2: masked scaled softmax (full-wave shuffles only) -------
    const int len = lens[b];
    float sc = -INFINITY;
    if (tid < HS) sc = ((tid < len) ? s_sc[tid] : -4294967296.0f) * 0.125f;
    float mx = sc;
    #pragma unroll
    for (int o = 32; o; o >>= 1) mx = fmaxf(mx, __shfl_xor(mx, o));
    if ((tid & 63) == 0) s_red[tid >> 6] = mx;
    __syncthreads();
    const float gmax = fmaxf(fmaxf(s_red[0], s_red[1]), fmaxf(s_red[2], s_red[3]));
    float e = 0.f;
    if (tid < HS) { e = __expf(sc - gmax); s_sc[tid] = e; }
    float sm = e;
    #pragma unroll
    for (int o = 32; o; o >>= 1) sm += __shfl_xor(sm, o);
    if ((tid & 63) == 0) s_red[4 + (tid >> 6)] = sm;
    __syncthreads();
    const float inv = 1.0f / ((s_red[4] + s_red[5]) + (s_red[6] + s_red[7]));

    // ---------------- P3: weighted sum from LDS bf16 ----------------------------
    {
        const int d = tid & 63, ch = tid >> 6;
        const int w = d >> 1;
        float accd = 0.f;
        for (int s = ch; s < HS; s += 4) {
            unsigned u = s_h[s * NW + swz(s, w)];
            float hv = __uint_as_float((d & 1) ? (u & 0xFFFF0000u) : (u << 16));
            accd = fmaf(s_sc[s], hv, accd);
        }
        s_part[tid] = accd;
    }
    __syncthreads();
    if (tid < DIMV) {
        float res = (s_part[tid] + s_part[DIMV + tid]) +
                    (s_part[2 * DIMV + tid] + s_part[3 * DIMV + tid]);
        out[(size_t)b * DIMV + tid] = res * inv;
    }
}

extern "C" void kernel_launch(void* const* d_in, const int* in_sizes, int n_in,
                              void* d_out, int out_size, void* d_ws, size_t ws_size,
                              hipStream_t stream) {
    const float* cand = (const float*)d_in[0];
    const float* hist = (const float*)d_in[1];
    const int*   lens = (const int*)d_in[2];
    const float* W1   = (const float*)d_in[3];
    const float* B1   = (const float*)d_in[4];
    const float* W2   = (const float*)d_in[5];
    const float* B2   = (const float*)d_in[6];
    float* out = (float*)d_out;

    const int B = in_sizes[0] / DIMV;  // 4096
    din_attn_kernel<<<B, NTH, 0, stream>>>(cand, hist, lens, W1, B1, W2, B2, out);
}

// Round 4
// 57.459 us; speedup vs baseline: 1.8407x; 1.5794x over previous
//
#include <hip/hip_runtime.h>
#include <math.h>

#define HS    200   // HIST_SIZE
#define DIMV  64    // DIM
#define HID   32    // HIDDEN
#define NTH   256

typedef __attribute__((ext_vector_type(8))) short short8;   // 8 bf16 (4 VGPRs)
typedef __attribute__((ext_vector_type(4))) float f32x4;    // MFMA acc

// round-to-nearest-even f32 -> bf16 (bits in low 16)
__device__ __forceinline__ unsigned bf16_rne(float x) {
    unsigned u = __float_as_uint(x);
    return (u + 0x7FFFu + ((u >> 16) & 1u)) >> 16;
}
__device__ __forceinline__ float bf16f(short x) {
    return __uint_as_float(((unsigned)(unsigned short)x) << 16);
}

// s_h: 208 rows x 64 ushort (128 B/row). 16-B groups XOR-swizzled by (row&7).
// s_Mt: 32 rows x 64 ushort, same swizzle. Both MFMA fragments read as one b128.

__global__ __launch_bounds__(NTH, 5) void din_attn_kernel(
    const float* __restrict__ cand,   // B x 64
    const float* __restrict__ hist,   // B x 200 x 64
    const int*   __restrict__ lens,   // B
    const float* __restrict__ W1,     // 256 x 32
    const float* __restrict__ B1,     // 32
    const float* __restrict__ W2,     // 32
    const float* __restrict__ B2,     // 1
    float* __restrict__ out)          // B x 64
{
    __shared__ __align__(16) unsigned short s_h[208 * 64];   // 26624 B
    __shared__ __align__(16) unsigned char  s_u[4096];       // Mt (P0/P1) | part (P3)
    __shared__ float s_sc[HS];          // 800 B
    __shared__ float s_c[HID];          // 128 B
    __shared__ float s_w2[HID];         // 128 B
    __shared__ float s_red[8];          // 32 B   -> 31808 B total (5 blocks/CU)

    unsigned short* s_Mt  = (unsigned short*)s_u;
    float*          s_part = (float*)s_u;

    const int b   = blockIdx.x;
    const int tid = threadIdx.x;

    // ---------------- P0: stage hist (bf16, swizzled) + build Mt(bf16), c -------
    const float4* hp = (const float4*)(hist + (size_t)b * (HS * DIMV));
    float4 v[13];
    #pragma unroll
    for (int j = 0; j < 12; ++j) v[j] = hp[tid + j * NTH];
    const bool tail = tid < (HS * DIMV / 4 - 12 * NTH);   // 128 threads
    if (tail) v[12] = hp[12 * NTH + tid];

    {   // Mt[h][f] = bf16( Wb[f][h] - Wd[f][h] + cand[f]*Wc[f][h] ), one b128/thread
        const int h = tid & 31, fg = tid >> 5;     // fg in 0..7, f = fg*8..fg*8+7
        const float* cb = cand + (size_t)b * DIMV + fg * 8;
        float4 cA = *(const float4*)cb;
        float4 cB = *(const float4*)(cb + 4);
        float cf[8] = {cA.x, cA.y, cA.z, cA.w, cB.x, cB.y, cB.z, cB.w};
        short8 mt;
        #pragma unroll
        for (int ff = 0; ff < 8; ++ff) {
            int f = fg * 8 + ff;
            float m = W1[(DIMV + f) * HID + h]
                    - W1[(3 * DIMV + f) * HID + h]
                    + cf[ff] * W1[(2 * DIMV + f) * HID + h];
            mt[ff] = (short)bf16_rne(m);
        }
        int pg = fg ^ (h & 7);
        *(short8*)&s_Mt[h * 64 + pg * 8] = mt;
    }
    if (tid < HID) {   // c[h] = sum_f cand[f]*(Wa+Wd)[f][h] + B1[h]
        float acc = B1[tid];
        #pragma unroll 8
        for (int f = 0; f < DIMV; ++f)
            acc += cand[(size_t)b * DIMV + f] *
                   (W1[f * HID + tid] + W1[(3 * DIMV + f) * HID + tid]);
        s_c[tid]  = acc;
        s_w2[tid] = W2[tid];
    }

    #pragma unroll
    for (int j = 0; j < 12; ++j) {
        int i = tid + j * NTH;              // float4 idx; row r has 16 of them
        int r = i >> 4;
        int g = (i & 15) >> 1, half = i & 1;
        int pg = g ^ (r & 7);
        unsigned lo = bf16_rne(v[j].x) | (bf16_rne(v[j].y) << 16);
        unsigned hi = bf16_rne(v[j].z) | (bf16_rne(v[j].w) << 16);
        *(uint2*)&s_h[r * 64 + pg * 8 + half * 4] = make_uint2(lo, hi);
    }
    if (tail) {
        int i = 12 * NTH + tid;
        int r = i >> 4, g = (i & 15) >> 1, half = i & 1;
        int pg = g ^ (r & 7);
        unsigned lo = bf16_rne(v[12].x) | (bf16_rne(v[12].y) << 16);
        unsigned hi = bf16_rne(v[12].z) | (bf16_rne(v[12].w) << 16);
        *(uint2*)&s_h[r * 64 + pg * 8 + half * 4] = make_uint2(lo, hi);
    }
    __syncthreads();

    // ---------------- P1: scores via MFMA (13 row-tiles over 4 waves) -----------
    {
        const int lane = tid & 63, wid = tid >> 6;
        const int lc = lane & 15, lg = lane >> 4;
        const float c0  = s_c[lc],       c1  = s_c[16 + lc];
        const float w20 = s_w2[lc],      w21 = s_w2[16 + lc];
        const float b2  = B2[0];

        // B fragments: B[k=f][j=h] from s_Mt[h][f] (row-major-in-h, swizzled)
        short8 b00 = *(const short8*)&s_Mt[lc * 64        + ((lg)     ^ (lc & 7)) * 8];
        short8 b01 = *(const short8*)&s_Mt[lc * 64        + ((4 + lg) ^ (lc & 7)) * 8];
        short8 b10 = *(const short8*)&s_Mt[(16 + lc) * 64 + ((lg)     ^ (lc & 7)) * 8];
        short8 b11 = *(const short8*)&s_Mt[(16 + lc) * 64 + ((4 + lg) ^ (lc & 7)) * 8];

        for (int rt = wid; rt < 13; rt += 4) {     // wave-uniform trip count
            int s = rt * 16 + lc;
            short8 a0 = *(const short8*)&s_h[s * 64 + ((lg)     ^ (s & 7)) * 8];
            short8 a1 = *(const short8*)&s_h[s * 64 + ((4 + lg) ^ (s & 7)) * 8];
            f32x4 z = {0.f, 0.f, 0.f, 0.f};
            f32x4 acc0 = __builtin_amdgcn_mfma_f32_16x16x32_bf16(a0, b00, z, 0, 0, 0);
            acc0       = __builtin_amdgcn_mfma_f32_16x16x32_bf16(a1, b01, acc0, 0, 0, 0);
            f32x4 acc1 = __builtin_amdgcn_mfma_f32_16x16x32_bf16(a0, b10, z, 0, 0, 0);
            acc1       = __builtin_amdgcn_mfma_f32_16x16x32_bf16(a1, b11, acc1, 0, 0, 0);
            // score partial: relu(H+c) dot W2 over this lane's two cols
            float p[4];
            #pragma unroll
            for (int r = 0; r < 4; ++r)
                p[r] = fmaxf(acc0[r] + c0, 0.f) * w20 + fmaxf(acc1[r] + c1, 0.f) * w21;
            #pragma unroll
            for (int r = 0; r < 4; ++r) {          // reduce over 16 cols (full wave)
                p[r] += __shfl_xor(p[r], 1);
                p[r] += __shfl_xor(p[r], 2);
                p[r] += __shfl_xor(p[r], 4);
                p[r] += __shfl_xor(p[r], 8);
            }
            if (lc == 0) {
                int rbase = rt * 16 + lg * 4;      // D row = 4*(lane>>4)+reg
                #pragma unroll
                for (int r = 0; r < 4; ++r)
                    if (rbase + r < HS) s_sc[rbase + r] = p[r] + b2;
            }
        }
    }
    __syncthreads();

    // ---------------- P2: masked scaled softmax (full-wave shuffles only) -------
    const int len = lens[b];
    float sc = -INFINITY;
    if (tid < HS) sc = ((tid < len) ? s_sc[tid] : -4294967296.0f) * 0.125f;
    float mx = sc;
    #pragma unroll
    for (int o = 32; o; o >>= 1) mx = fmaxf(mx, __shfl_xor(mx, o));
    if ((tid & 63) == 0) s_red[tid >> 6] = mx;
    __syncthreads();
    const float gmax = fmaxf(fmaxf(s_red[0], s_red[1]), fmaxf(s_red[2], s_red[3]));
    float e = 0.f;
    if (tid < HS) { e = __expf(sc - gmax); s_sc[tid] = e; }
    float sm = e;
    #pragma unroll
    for (int o = 32; o; o >>= 1) sm += __shfl_xor(sm, o);
    if ((tid & 63) == 0) s_red[4 + (tid >> 6)] = sm;
    __syncthreads();
    const float inv = 1.0f / ((s_red[4] + s_red[5]) + (s_red[6] + s_red[7]));

    // ---------------- P3: weighted sum (vector b128 reads + butterfly) ----------
    {
        const int lane = tid & 63, wid = tid >> 6;
        float a3[8] = {0.f, 0.f, 0.f, 0.f, 0.f, 0.f, 0.f, 0.f};
        for (int rb = wid; rb < 25; rb += 4) {     // wave-uniform trip count
            int s = rb * 8 + (lane >> 3);
            int g = lane & 7;                      // d-range g*8..g*8+7
            short8 hv = *(const short8*)&s_h[s * 64 + (g ^ (s & 7)) * 8];
            float wgt = s_sc[s];
            #pragma unroll
            for (int j = 0; j < 8; ++j) a3[j] = fmaf(wgt, bf16f(hv[j]), a3[j]);
        }
        #pragma unroll
        for (int off = 8; off < 64; off <<= 1)     // reduce across 8 row-stripes
            #pragma unroll
            for (int j = 0; j < 8; ++j) a3[j] += __shfl_xor(a3[j], off);
        if (lane < 8) {
            float* dst = &s_part[wid * 64 + lane * 8];
            *(float4*)dst       = make_float4(a3[0], a3[1], a3[2], a3[3]);
            *(float4*)(dst + 4) = make_float4(a3[4], a3[5], a3[6], a3[7]);
        }
    }
    __syncthreads();
    if (tid < DIMV) {
        float res = (s_part[tid] + s_part[DIMV + tid]) +
                    (s_part[2 * DIMV + tid] + s_part[3 * DIMV + tid]);
        out[(size_t)b * DIMV + tid] = res * inv;
    }
}

extern "C" void kernel_launch(void* const* d_in, const int* in_sizes, int n_in,
                              void* d_out, int out_size, void* d_ws, size_t ws_size,
                              hipStream_t stream) {
    const float* cand = (const float*)d_in[0];
    const float* hist = (const float*)d_in[1];
    const int*   lens = (const int*)d_in[2];
    const float* W1   = (const float*)d_in[3];
    const float* B1   = (const float*)d_in[4];
    const float* W2   = (const float*)d_in[5];
    const float* B2   = (const float*)d_in[6];
    float* out = (float*)d_out;

    const int B = in_sizes[0] / DIMV;  // 4096
    din_attn_kernel<<<B, NTH, 0, stream>>>(cand, hist, lens, W1, B1, W2, B2, out);
}

// Round 5
// 54.315 us; speedup vs baseline: 1.9472x; 1.0579x over previous
//
#include <hip/hip_runtime.h>
#include <math.h>

#define HS    200   // HIST_SIZE
#define DIMV  64    // DIM
#define HID   32    // HIDDEN
#define NTH   256

typedef __attribute__((ext_vector_type(8))) short short8;   // 8 bf16 (4 VGPRs)
typedef __attribute__((ext_vector_type(4))) float f32x4;    // MFMA acc
typedef __bf16 bf2_t __attribute__((ext_vector_type(2)));
typedef float  f2_t  __attribute__((ext_vector_type(2)));

// packed f32x2 -> bf16x2 (RNE), expected to lower to v_cvt_pk_bf16_f32
__device__ __forceinline__ unsigned cvt2(float x, float y) {
    f2_t f = {x, y};
    bf2_t bv = __builtin_convertvector(f, bf2_t);
    union { bf2_t b; unsigned u; } un;
    un.b = bv;
    return un.u;
}
__device__ __forceinline__ float bf16f(short x) {
    return __uint_as_float(((unsigned)(unsigned short)x) << 16);
}

// s_h: 208 rows x 64 ushort (128 B/row). 16-B groups XOR-swizzled by (row&7).
// s_Mt: 32 rows x 64 ushort, same swizzle. Both MFMA fragments read as one b128.

__global__ __launch_bounds__(NTH, 5) void din_attn_kernel(
    const float* __restrict__ cand,   // B x 64
    const float* __restrict__ hist,   // B x 200 x 64
    const int*   __restrict__ lens,   // B
    const float* __restrict__ W1,     // 256 x 32
    const float* __restrict__ B1,     // 32
    const float* __restrict__ W2,     // 32
    const float* __restrict__ B2,     // 1
    float* __restrict__ out)          // B x 64
{
    __shared__ __align__(16) unsigned short s_h[208 * 64];   // 26624 B
    __shared__ __align__(16) unsigned char  s_u[4096];       // Mt (P0/P1) | part (P3)
    __shared__ float s_sc[208];         // 832 B (pad: P1 writes rows 200..207)
    __shared__ float s_c[HID];          // 128 B
    __shared__ float s_w2[HID];         // 128 B
    __shared__ float s_red[8];          // 32 B   -> ~31.9 KB total (5 blocks/CU)

    unsigned short* s_Mt   = (unsigned short*)s_u;
    float*          s_part = (float*)s_u;

    const int b   = blockIdx.x;
    const int tid = threadIdx.x;

    // ---------------- P0: stage hist (bf16, swizzled) + build Mt(bf16), c -------
    // 3200 float4 = 1600 pairs; each pair = one 16-B swizzle group = one b128 write.
    const float4* hp = (const float4*)(hist + (size_t)b * (HS * DIMV));
    float4 va[7], vb[7];
    #pragma unroll
    for (int j = 0; j < 6; ++j) {
        int pi = tid + j * NTH;
        va[j] = hp[2 * pi];
        vb[j] = hp[2 * pi + 1];
    }
    const bool tail = tid < (1600 - 6 * NTH);   // 64 threads
    if (tail) {
        int pi = 6 * NTH + tid;
        va[6] = hp[2 * pi];
        vb[6] = hp[2 * pi + 1];
    }

    {   // Mt[h][f] = bf16( Wb[f][h] - Wd[f][h] + cand[f]*Wc[f][h] ), one b128/thread
        const int h = tid & 31, fg = tid >> 5;     // fg in 0..7, f = fg*8..fg*8+7
        const float* cb = cand + (size_t)b * DIMV + fg * 8;
        float4 cA = *(const float4*)cb;
        float4 cB = *(const float4*)(cb + 4);
        float cf[8] = {cA.x, cA.y, cA.z, cA.w, cB.x, cB.y, cB.z, cB.w};
        float m[8];
        #pragma unroll
        for (int ff = 0; ff < 8; ++ff) {
            int f = fg * 8 + ff;
            m[ff] = W1[(DIMV + f) * HID + h]
                  - W1[(3 * DIMV + f) * HID + h]
                  + cf[ff] * W1[(2 * DIMV + f) * HID + h];
        }
        uint4 mw = make_uint4(cvt2(m[0], m[1]), cvt2(m[2], m[3]),
                              cvt2(m[4], m[5]), cvt2(m[6], m[7]));
        int pg = fg ^ (h & 7);
        *(uint4*)&s_Mt[h * 64 + pg * 8] = mw;
    }
    if (tid < HID) {   // c[h] = sum_f cand[f]*(Wa+Wd)[f][h] + B1[h]
        float acc = B1[tid];
        #pragma unroll 8
        for (int f = 0; f < DIMV; ++f)
            acc += cand[(size_t)b * DIMV + f] *
                   (W1[f * HID + tid] + W1[(3 * DIMV + f) * HID + tid]);
        s_c[tid]  = acc;
        s_w2[tid] = W2[tid];
    }

    #pragma unroll
    for (int j = 0; j < 6; ++j) {
        int pi = tid + j * NTH;             // pair index; 8 pairs per row
        int r = pi >> 3, g = pi & 7;
        int pg = g ^ (r & 7);
        uint4 w = make_uint4(cvt2(va[j].x, va[j].y), cvt2(va[j].z, va[j].w),
                             cvt2(vb[j].x, vb[j].y), cvt2(vb[j].z, vb[j].w));
        *(uint4*)&s_h[r * 64 + pg * 8] = w;
    }
    if (tail) {
        int pi = 6 * NTH + tid;
        int r = pi >> 3, g = pi & 7;
        int pg = g ^ (r & 7);
        uint4 w = make_uint4(cvt2(va[6].x, va[6].y), cvt2(va[6].z, va[6].w),
                             cvt2(vb[6].x, vb[6].y), cvt2(vb[6].z, vb[6].w));
        *(uint4*)&s_h[r * 64 + pg * 8] = w;
    }
    __syncthreads();

    // ---------------- P1: scores via MFMA (13 row-tiles over 4 waves) -----------
    {
        const int lane = tid & 63, wid = tid >> 6;
        const int lc = lane & 15, lg = lane >> 4;
        const float c0  = s_c[lc],       c1  = s_c[16 + lc];
        const float w20 = s_w2[lc],      w21 = s_w2[16 + lc];
        const float b2  = B2[0];

        // B fragments: B[k=f][j=h] from s_Mt[h][f] (row-major-in-h, swizzled)
        short8 b00 = *(const short8*)&s_Mt[lc * 64        + ((lg)     ^ (lc & 7)) * 8];
        short8 b01 = *(const short8*)&s_Mt[lc * 64        + ((4 + lg) ^ (lc & 7)) * 8];
        short8 b10 = *(const short8*)&s_Mt[(16 + lc) * 64 + ((lg)     ^ (lc & 7)) * 8];
        short8 b11 = *(const short8*)&s_Mt[(16 + lc) * 64 + ((4 + lg) ^ (lc & 7)) * 8];

        for (int rt = wid; rt < 13; rt += 4) {     // wave-uniform trip count
            int s = rt * 16 + lc;
            short8 a0 = *(const short8*)&s_h[s * 64 + ((lg)     ^ (s & 7)) * 8];
            short8 a1 = *(const short8*)&s_h[s * 64 + ((4 + lg) ^ (s & 7)) * 8];
            f32x4 z = {0.f, 0.f, 0.f, 0.f};
            f32x4 acc0 = __builtin_amdgcn_mfma_f32_16x16x32_bf16(a0, b00, z, 0, 0, 0);
            acc0       = __builtin_amdgcn_mfma_f32_16x16x32_bf16(a1, b01, acc0, 0, 0, 0);
            f32x4 acc1 = __builtin_amdgcn_mfma_f32_16x16x32_bf16(a0, b10, z, 0, 0, 0);
            acc1       = __builtin_amdgcn_mfma_f32_16x16x32_bf16(a1, b11, acc1, 0, 0, 0);
            // score partial: relu(H+c) dot W2 over this lane's two cols
            float p[4];
            #pragma unroll
            for (int r = 0; r < 4; ++r)
                p[r] = fmaxf(acc0[r] + c0, 0.f) * w20 + fmaxf(acc1[r] + c1, 0.f) * w21;
            #pragma unroll
            for (int r = 0; r < 4; ++r) {          // reduce over 16 cols (full wave)
                p[r] += __shfl_xor(p[r], 1);
                p[r] += __shfl_xor(p[r], 2);
                p[r] += __shfl_xor(p[r], 4);
                p[r] += __shfl_xor(p[r], 8);
            }
            if (lc == 0) {
                int rbase = rt * 16 + lg * 4;      // D row = 4*(lane>>4)+reg
                #pragma unroll
                for (int r = 0; r < 4; ++r) s_sc[rbase + r] = p[r] + b2;
            }
        }
    }
    __syncthreads();

    // ---------------- P2: masked scaled softmax (full-wave shuffles only) -------
    const int len = lens[b];
    float sc = -INFINITY;
    if (tid < HS) sc = ((tid < len) ? s_sc[tid] : -4294967296.0f) * 0.125f;
    float mx = sc;
    #pragma unroll
    for (int o = 32; o; o >>= 1) mx = fmaxf(mx, __shfl_xor(mx, o));
    if ((tid & 63) == 0) s_red[tid >> 6] = mx;
    __syncthreads();
    const float gmax = fmaxf(fmaxf(s_red[0], s_red[1]), fmaxf(s_red[2], s_red[3]));
    float e = 0.f;
    if (tid < HS) { e = __expf(sc - gmax); s_sc[tid] = e; }
    float sm = e;
    #pragma unroll
    for (int o = 32; o; o >>= 1) sm += __shfl_xor(sm, o);
    if ((tid & 63) == 0) s_red[4 + (tid >> 6)] = sm;
    __syncthreads();
    const float inv = 1.0f / ((s_red[4] + s_red[5]) + (s_red[6] + s_red[7]));

    // ---------------- P3: weighted sum (vector b128 reads + butterfly) ----------
    {
        const int lane = tid & 63, wid = tid >> 6;
        float a3[8] = {0.f, 0.f, 0.f, 0.f, 0.f, 0.f, 0.f, 0.f};
        for (int rb = wid; rb < 25; rb += 4) {     // wave-uniform trip count
            int s = rb * 8 + (lane >> 3);
            int g = lane & 7;                      // d-range g*8..g*8+7
            short8 hv = *(const short8*)&s_h[s * 64 + (g ^ (s & 7)) * 8];
            float wgt = s_sc[s];
            #pragma unroll
            for (int j = 0; j < 8; ++j) a3[j] = fmaf(wgt, bf16f(hv[j]), a3[j]);
        }
        #pragma unroll
        for (int off = 8; off < 64; off <<= 1)     // reduce across 8 row-stripes
            #pragma unroll
            for (int j = 0; j < 8; ++j) a3[j] += __shfl_xor(a3[j], off);
        if (lane < 8) {
            float* dst = &s_part[wid * 64 + lane * 8];
            *(float4*)dst       = make_float4(a3[0], a3[1], a3[2], a3[3]);
            *(float4*)(dst + 4) = make_float4(a3[4], a3[5], a3[6], a3[7]);
        }
    }
    __syncthreads();
    if (tid < DIMV) {
        float res = (s_part[tid] + s_part[DIMV + tid]) +
                    (s_part[2 * DIMV + tid] + s_part[3 * DIMV + tid]);
        out[(size_t)b * DIMV + tid] = res * inv;
    }
}

extern "C" void kernel_launch(void* const* d_in, const int* in_sizes, int n_in,
                              void* d_out, int out_size, void* d_ws, size_t ws_size,
                              hipStream_t stream) {
    const float* cand = (const float*)d_in[0];
    const float* hist = (const float*)d_in[1];
    const int*   lens = (const int*)d_in[2];
    const float* W1   = (const float*)d_in[3];
    const float* B1   = (const float*)d_in[4];
    const float* W2   = (const float*)d_in[5];
    const float* B2   = (const float*)d_in[6];
    float* out = (float*)d_out;

    const int B = in_sizes[0] / DIMV;  // 4096
    din_attn_kernel<<<B, NTH, 0, stream>>>(cand, hist, lens, W1, B1, W2, B2, out);
}

// Round 6
// 44.997 us; speedup vs baseline: 2.3505x; 1.2071x over previous
//
#include <hip/hip_runtime.h>
#include <math.h>

#define HS    200   // HIST_SIZE
#define DIMV  64    // DIM
#define HID   32    // HIDDEN
#define NTH   512

typedef __attribute__((ext_vector_type(8))) short short8;   // 8 bf16 (4 VGPRs)
typedef __attribute__((ext_vector_type(4))) float f32x4;    // MFMA acc
typedef __bf16 bf2_t __attribute__((ext_vector_type(2)));
typedef float  f2_t  __attribute__((ext_vector_type(2)));

// packed f32x2 -> bf16x2 (RNE) -> v_cvt_pk_bf16_f32
__device__ __forceinline__ unsigned cvt2(float x, float y) {
    f2_t f = {x, y};
    bf2_t bv = __builtin_convertvector(f, bf2_t);
    union { bf2_t b; unsigned u; } un;
    un.b = bv;
    return un.u;
}
__device__ __forceinline__ float bf16f(short x) {
    return __uint_as_float(((unsigned)(unsigned short)x) << 16);
}

// DPP cross-lane (VALU pipe, no lgkmcnt): row_ror:N = 0x120|N, quad_perm, mirrors
template<int CTRL>
__device__ __forceinline__ float dpp_add(float x) {
    int y = __builtin_amdgcn_update_dpp(0, __float_as_int(x), CTRL, 0xF, 0xF, true);
    return x + __int_as_float(y);
}
template<int CTRL>
__device__ __forceinline__ float dpp_max(float x) {
    int y = __builtin_amdgcn_update_dpp(0, __float_as_int(x), CTRL, 0xF, 0xF, true);
    return fmaxf(x, __int_as_float(y));
}
#define ROR1  0x121
#define ROR2  0x122
#define ROR4  0x124
#define ROR8  0x128
#define QXOR1 0xB1   // quad_perm [1,0,3,2]
#define QXOR2 0x4E   // quad_perm [2,3,0,1]
#define HMIRR 0x141  // row_half_mirror
__device__ __forceinline__ float swz_xor16(float x) {  // lane ^ 16 (within 32)
    return __int_as_float(__builtin_amdgcn_ds_swizzle(__float_as_int(x), 0x401F));
}

// s_h: 208 rows x 64 ushort (128 B/row). 16-B groups XOR-swizzled by (row&7).
// s_Mt: 32 rows x 64 ushort, same swizzle.

__global__ __launch_bounds__(NTH, 8) void din_attn_kernel(
    const float* __restrict__ cand,   // B x 64
    const float* __restrict__ hist,   // B x 200 x 64
    const int*   __restrict__ lens,   // B
    const float* __restrict__ W1,     // 256 x 32
    const float* __restrict__ B1,     // 32
    const float* __restrict__ W2,     // 32
    const float* __restrict__ B2,     // 1
    float* __restrict__ out)          // B x 64
{
    __shared__ __align__(16) unsigned short s_h[208 * 64];   // 26624 B
    __shared__ __align__(16) unsigned char  s_u[4096];       // Mt (P0/P1) | part (P3)
    __shared__ float s_sc[208];         // 832 B
    __shared__ float s_c[HID];          // 128 B
    __shared__ float s_w2[HID];         // 128 B
    __shared__ float s_red[16];         // 64 B   -> 31872 B total (4 blocks/CU)

    unsigned short* s_Mt   = (unsigned short*)s_u;
    float*          s_part = (float*)s_u;            // 8 waves x 64 f = 2 KB

    const int b   = blockIdx.x;
    const int tid = threadIdx.x;
    const float* cb = cand + (size_t)b * DIMV;

    // ---------------- P0: stage hist (bf16, swizzled); Mt by waves 0-3, c by 4-7
    const float4* hp = (const float4*)(hist + (size_t)b * (HS * DIMV));
    float4 va[4], vb[4];
    #pragma unroll
    for (int j = 0; j < 3; ++j) {
        int pi = tid + j * NTH;
        va[j] = hp[2 * pi];
        vb[j] = hp[2 * pi + 1];
    }
    const bool tail = tid < (1600 - 3 * NTH);   // 64 threads
    if (tail) {
        int pi = 3 * NTH + tid;
        va[3] = hp[2 * pi];
        vb[3] = hp[2 * pi + 1];
    }

    if (tid < 256) {   // Mt[h][f] = bf16(Wb - Wd + cand[f]*Wc), one b128/thread
        const int h = tid & 31, fg = tid >> 5;     // f = fg*8..fg*8+7
        float4 cA = *(const float4*)(cb + fg * 8);
        float4 cB = *(const float4*)(cb + fg * 8 + 4);
        float cf[8] = {cA.x, cA.y, cA.z, cA.w, cB.x, cB.y, cB.z, cB.w};
        float m[8];
        #pragma unroll
        for (int ff = 0; ff < 8; ++ff) {
            int f = fg * 8 + ff;
            m[ff] = W1[(DIMV + f) * HID + h]
                  - W1[(3 * DIMV + f) * HID + h]
                  + cf[ff] * W1[(2 * DIMV + f) * HID + h];
        }
        uint4 mw = make_uint4(cvt2(m[0], m[1]), cvt2(m[2], m[3]),
                              cvt2(m[4], m[5]), cvt2(m[6], m[7]));
        int pg = fg ^ (h & 7);
        *(uint4*)&s_Mt[h * 64 + pg * 8] = mw;
        if (tid < HID) s_w2[tid] = W2[tid];
    } else {           // c[h] = sum_f cand[f]*(Wa+Wd)[f][h] + B1[h], 8-way split
        const int t2 = tid - 256;
        const int h = t2 >> 3, fg = t2 & 7;
        float p = 0.f;
        #pragma unroll
        for (int ff = 0; ff < 8; ++ff) {
            int f = fg * 8 + ff;
            p += cb[f] * (W1[f * HID + h] + W1[(3 * DIMV + f) * HID + h]);
        }
        p = dpp_add<QXOR1>(p);     // xor1 within quad
        p = dpp_add<QXOR2>(p);     // xor2 within quad
        p = dpp_add<HMIRR>(p);     // merge 4-quads within 8-lane half
        if ((tid & 7) == 0) s_c[h] = p + B1[h];
    }

    #pragma unroll
    for (int j = 0; j < 3; ++j) {
        int pi = tid + j * NTH;             // pair index; 8 pairs per row
        int r = pi >> 3, g = pi & 7;
        int pg = g ^ (r & 7);
        uint4 w = make_uint4(cvt2(va[j].x, va[j].y), cvt2(va[j].z, va[j].w),
                             cvt2(vb[j].x, vb[j].y), cvt2(vb[j].z, vb[j].w));
        *(uint4*)&s_h[r * 64 + pg * 8] = w;
    }
    if (tail) {
        int pi = 3 * NTH + tid;
        int r = pi >> 3, g = pi & 7;
        int pg = g ^ (r & 7);
        uint4 w = make_uint4(cvt2(va[3].x, va[3].y), cvt2(va[3].z, va[3].w),
                             cvt2(vb[3].x, vb[3].y), cvt2(vb[3].z, vb[3].w));
        *(uint4*)&s_h[r * 64 + pg * 8] = w;
    }
    __syncthreads();

    // ---------------- P1: scores via MFMA (13 row-tiles over 8 waves) -----------
    {
        const int lane = tid & 63, wid = tid >> 6;
        const int lc = lane & 15, lg = lane >> 4;
        const float c0  = s_c[lc],       c1  = s_c[16 + lc];
        const float w20 = s_w2[lc],      w21 = s_w2[16 + lc];
        const float b2  = B2[0];

        short8 b00 = *(const short8*)&s_Mt[lc * 64        + ((lg)     ^ (lc & 7)) * 8];
        short8 b01 = *(const short8*)&s_Mt[lc * 64        + ((4 + lg) ^ (lc & 7)) * 8];
        short8 b10 = *(const short8*)&s_Mt[(16 + lc) * 64 + ((lg)     ^ (lc & 7)) * 8];
        short8 b11 = *(const short8*)&s_Mt[(16 + lc) * 64 + ((4 + lg) ^ (lc & 7)) * 8];

        for (int rt = wid; rt < 13; rt += 8) {     // wave-uniform trip count
            int s = rt * 16 + lc;
            short8 a0 = *(const short8*)&s_h[s * 64 + ((lg)     ^ (s & 7)) * 8];
            short8 a1 = *(const short8*)&s_h[s * 64 + ((4 + lg) ^ (s & 7)) * 8];
            f32x4 z = {0.f, 0.f, 0.f, 0.f};
            f32x4 acc0 = __builtin_amdgcn_mfma_f32_16x16x32_bf16(a0, b00, z, 0, 0, 0);
            acc0       = __builtin_amdgcn_mfma_f32_16x16x32_bf16(a1, b01, acc0, 0, 0, 0);
            f32x4 acc1 = __builtin_amdgcn_mfma_f32_16x16x32_bf16(a0, b10, z, 0, 0, 0);
            acc1       = __builtin_amdgcn_mfma_f32_16x16x32_bf16(a1, b11, acc1, 0, 0, 0);
            float p[4];
            #pragma unroll
            for (int r = 0; r < 4; ++r)
                p[r] = fmaxf(acc0[r] + c0, 0.f) * w20 + fmaxf(acc1[r] + c1, 0.f) * w21;
            #pragma unroll
            for (int r = 0; r < 4; ++r) {          // 16-lane rotate-reduce, VALU pipe
                p[r] = dpp_add<ROR1>(p[r]);
                p[r] = dpp_add<ROR2>(p[r]);
                p[r] = dpp_add<ROR4>(p[r]);
                p[r] = dpp_add<ROR8>(p[r]);
            }
            if (lc == 0) {
                int rbase = rt * 16 + lg * 4;      // D row = 4*(lane>>4)+reg
                #pragma unroll
                for (int r = 0; r < 4; ++r) s_sc[rbase + r] = p[r] + b2;
            }
        }
    }
    __syncthreads();

    // ---------------- P2: masked scaled softmax ---------------------------------
    const int len = lens[b];
    const int wid = tid >> 6;
    float sc = -INFINITY;
    if (tid < HS) sc = ((tid < len) ? s_sc[tid] : -4294967296.0f) * 0.125f;
    float mx = sc;
    mx = dpp_max<ROR1>(mx); mx = dpp_max<ROR2>(mx);
    mx = dpp_max<ROR4>(mx); mx = dpp_max<ROR8>(mx);
    mx = fmaxf(mx, swz_xor16(mx));
    mx = fmaxf(mx, __shfl_xor(mx, 32));
    if ((tid & 63) == 0) s_red[wid] = mx;
    __syncthreads();
    float gmax = s_red[0];
    #pragma unroll
    for (int k = 1; k < 8; ++k) gmax = fmaxf(gmax, s_red[k]);
    float e = 0.f;
    if (tid < HS) { e = __expf(sc - gmax); s_sc[tid] = e; }
    float sm = e;
    sm = dpp_add<ROR1>(sm); sm = dpp_add<ROR2>(sm);
    sm = dpp_add<ROR4>(sm); sm = dpp_add<ROR8>(sm);
    sm += swz_xor16(sm);
    sm += __shfl_xor(sm, 32);
    if ((tid & 63) == 0) s_red[8 + wid] = sm;
    __syncthreads();
    float den = s_red[8];
    #pragma unroll
    for (int k = 9; k < 16; ++k) den += s_red[k];
    const float inv = 1.0f / den;

    // ---------------- P3: weighted sum (b128 reads + hybrid reduce) -------------
    {
        const int lane = tid & 63;
        float a3[8] = {0.f, 0.f, 0.f, 0.f, 0.f, 0.f, 0.f, 0.f};
        for (int rb = wid; rb < 25; rb += 8) {     // wave-uniform trip count
            int s = rb * 8 + (lane >> 3);
            int g = lane & 7;                      // d-range g*8..g*8+7
            short8 hv = *(const short8*)&s_h[s * 64 + (g ^ (s & 7)) * 8];
            float wgt = s_sc[s];
            #pragma unroll
            for (int j = 0; j < 8; ++j) a3[j] = fmaf(wgt, bf16f(hv[j]), a3[j]);
        }
        #pragma unroll
        for (int j = 0; j < 8; ++j) {              // reduce over lane bits 3,4,5
            float x = dpp_add<ROR8>(a3[j]);        // bit3 (within 16-row)
            x += swz_xor16(x);                     // bit4
            x += __shfl_xor(x, 32);                // bit5
            a3[j] = x;
        }
        if (lane < 8) {
            float* dst = &s_part[wid * 64 + lane * 8];
            *(float4*)dst       = make_float4(a3[0], a3[1], a3[2], a3[3]);
            *(float4*)(dst + 4) = make_float4(a3[4], a3[5], a3[6], a3[7]);
        }
    }
    __syncthreads();
    if (tid < DIMV) {
        float res = 0.f;
        #pragma unroll
        for (int k = 0; k < 8; ++k) res += s_part[k * 64 + tid];
        out[(size_t)b * DIMV + tid] = res * inv;
    }
}

extern "C" void kernel_launch(void* const* d_in, const int* in_sizes, int n_in,
                              void* d_out, int out_size, void* d_ws, size_t ws_size,
                              hipStream_t stream) {
    const float* cand = (const float*)d_in[0];
    const float* hist = (const float*)d_in[1];
    const int*   lens = (const int*)d_in[2];
    const float* W1   = (const float*)d_in[3];
    const float* B1   = (const float*)d_in[4];
    const float* W2   = (const float*)d_in[5];
    const float* B2   = (const float*)d_in[6];
    float* out = (float*)d_out;

    const int B = in_sizes[0] / DIMV;  // 4096
    din_attn_kernel<<<B, NTH, 0, stream>>>(cand, hist, lens, W1, B1, W2, B2, out);
}